// Round 10
// baseline (218.107 us; speedup 1.0000x reference)
//
#include <hip/hip_runtime.h>
#include <hip/hip_bf16.h>

// ---------------------------------------------------------------------------
// MultiheadAttention: x[2,2048,1024] fp32 -> out[2,2048,1024] fp32. H=16, D=64.
// Traffic-minimized pipeline (L2/L3 streaming ~7 TB/s is the shared wall):
//   0) casts   : x -> xb bf16, wqkv -> wqkvb bf16, BOTH into d_out (dead as
//                output until out_gemm rewrites it; 8+6=14 MB <= 16 MB).
//   1) qkv_gemm: 128x128 LDS-staged bf16 MFMA GEMM, both operands bf16.
//                XCD-aware 1-D grid: xcd=bid&7 owns 3 n-tiles x 32 m-tiles so
//                its B tiles stay L2-resident -> L3 traffic ~70 MB.
//                -> Q (pre-scaled log2e/8), K [BH,S,D], Vt [BH,D,S] bf16 in ws.
//   2) attn    : transposed flash attention (unshifted base-2 softmax,
//                in-register P transpose via interleaved key tiling),
//                cooperative K/V LDS staging shared by 4 waves. Unchanged.
//   2b) cast wo -> wob bf16 into Q slot (dead after attn).
//   3) out_gemm: 128x128 bf16 GEMM, XCD-aware grid (1 n-tile per XCD).
// ws (32 MiB): [Q 8 | K 8 | Vt 8 | AO 8]; wob overlays Q after attn.
// MFMA 16x16x32 bf16 layouts (m89/m91 verified):
//   A-frag: lane holds A[m=lane&15][k=(lane>>4)*8+j]
//   B-frag: lane holds B[k=(lane>>4)*8+j][n=lane&15]
//   C/D   : lane holds D[row=(lane>>4)*4+i][col=lane&15]
// ---------------------------------------------------------------------------

typedef __attribute__((ext_vector_type(8))) short bf16x8;
typedef __attribute__((ext_vector_type(4))) short bf16x4;
typedef __attribute__((ext_vector_type(4))) float f32x4;

#define MFMA16(a, b, c) __builtin_amdgcn_mfma_f32_16x16x32_bf16((a), (b), (c), 0, 0, 0)

#if __has_builtin(__builtin_amdgcn_exp2f)
#define EXP2F(x) __builtin_amdgcn_exp2f(x)
#else
#define EXP2F(x) exp2f(x)
#endif

static __device__ __forceinline__ unsigned short f2bf_bits(float v) {
    __hip_bfloat16 h = __float2bfloat16(v);
    return *reinterpret_cast<unsigned short*>(&h);
}

static __device__ __forceinline__ bf16x8 cvt8(const float* p) {
    const f32x4 a = reinterpret_cast<const f32x4*>(p)[0];
    const f32x4 b = reinterpret_cast<const f32x4*>(p)[1];
    bf16x8 r;
    r[0] = (short)f2bf_bits(a[0]); r[1] = (short)f2bf_bits(a[1]);
    r[2] = (short)f2bf_bits(a[2]); r[3] = (short)f2bf_bits(a[3]);
    r[4] = (short)f2bf_bits(b[0]); r[5] = (short)f2bf_bits(b[1]);
    r[6] = (short)f2bf_bits(b[2]); r[7] = (short)f2bf_bits(b[3]);
    return r;
}

__device__ __forceinline__ bf16x8 ldg8(const __hip_bfloat16* p) {
    return *reinterpret_cast<const bf16x8*>(p);
}

// ---------------------------------------------------------------------------
// Kernel 0: fp32 -> bf16 cast, 32 elems/thread.
// ---------------------------------------------------------------------------
__global__ __launch_bounds__(256)
void cast_f32_bf16(const float* __restrict__ src, __hip_bfloat16* __restrict__ dst) {
    const size_t base = ((size_t)blockIdx.x * 256 + threadIdx.x) * 32;
#pragma unroll
    for (int i = 0; i < 4; ++i)
        *reinterpret_cast<bf16x8*>(dst + base + i * 8) = cvt8(src + base + i * 8);
}

// ---------------------------------------------------------------------------
// Kernel 1: QKV projection, 128x128 tile, A=xb bf16, B=wqkvb bf16.
// 1-D grid 768 = 8 xcd x 3 n-tiles x 32 m-tiles (XCD-resident B tiles).
// Q pre-scaled by (1/8)*log2(e).
// ---------------------------------------------------------------------------
__global__ __launch_bounds__(256)
void qkv_gemm(const __hip_bfloat16* __restrict__ xb,
              const __hip_bfloat16* __restrict__ wb,
              const float* __restrict__ bqkv,
              __hip_bfloat16* __restrict__ Q,
              __hip_bfloat16* __restrict__ K,
              __hip_bfloat16* __restrict__ Vt) {
    __shared__ unsigned short As[128 * 40];
    __shared__ unsigned short Bs[128 * 40];

    const int tid  = threadIdx.x;
    const int lane = tid & 63;
    const int wv   = tid >> 6;
    const int quad = lane >> 4;
    const int l16  = lane & 15;
    const int wm   = wv >> 1;
    const int wn   = wv & 1;

    // XCD-aware tile mapping: xcd owns n-tiles [3*xcd, 3*xcd+3), all 32 m-tiles
    const int bid = blockIdx.x;          // 0..767
    const int xcd = bid & 7;
    const int r   = bid >> 3;            // 0..95
    const int m0  = (r / 3) * 128;
    const int n0  = (xcd * 3 + (r % 3)) * 128;

    const int sr = tid >> 1;             // 0..127
    const int sc = (tid & 1) * 16;       // 0,16
    const __hip_bfloat16* ag = xb + (size_t)(m0 + sr) * 1024 + sc;
    const __hip_bfloat16* bg = wb + (size_t)(n0 + sr) * 1024 + sc;
    unsigned short* aw = &As[sr * 40 + sc];
    unsigned short* bw = &Bs[sr * 40 + sc];

    f32x4 zv = {0.f, 0.f, 0.f, 0.f};
    f32x4 acc[4][4];
#pragma unroll
    for (int ii = 0; ii < 4; ++ii)
#pragma unroll
        for (int jj = 0; jj < 4; ++jj) acc[ii][jj] = zv;

    for (int k0 = 0; k0 < 1024; k0 += 32) {
        const bf16x8 av0 = ldg8(ag + k0), av1 = ldg8(ag + k0 + 8);
        const bf16x8 bv0 = ldg8(bg + k0), bv1 = ldg8(bg + k0 + 8);
        __syncthreads();
        reinterpret_cast<bf16x8*>(aw)[0] = av0;
        reinterpret_cast<bf16x8*>(aw)[1] = av1;
        reinterpret_cast<bf16x8*>(bw)[0] = bv0;
        reinterpret_cast<bf16x8*>(bw)[1] = bv1;
        __syncthreads();
        bf16x8 af[4], bf[4];
#pragma unroll
        for (int ii = 0; ii < 4; ++ii)
            af[ii] = *reinterpret_cast<const bf16x8*>(
                &As[(wm * 64 + ii * 16 + l16) * 40 + quad * 8]);
#pragma unroll
        for (int jj = 0; jj < 4; ++jj)
            bf[jj] = *reinterpret_cast<const bf16x8*>(
                &Bs[(wn * 64 + jj * 16 + l16) * 40 + quad * 8]);
#pragma unroll
        for (int ii = 0; ii < 4; ++ii)
#pragma unroll
            for (int jj = 0; jj < 4; ++jj)
                acc[ii][jj] = MFMA16(af[ii], bf[jj], acc[ii][jj]);
    }

    const float QSCALE = 0.18033688011f;   // 0.125 * log2(e)

#pragma unroll
    for (int jj = 0; jj < 4; ++jj) {
        const int n = n0 + wn * 64 + jj * 16 + l16;
        const float bias = bqkv[n];
        const int h = n / 192;
        const int r2 = n - h * 192;
        const int t = r2 >> 6;              // 0=Q 1=K 2=V
        const int d = r2 & 63;
#pragma unroll
        for (int ii = 0; ii < 4; ++ii) {
#pragma unroll
            for (int i = 0; i < 4; ++i) {
                const int m = m0 + wm * 64 + ii * 16 + quad * 4 + i;
                const int b = m >> 11;
                const int s = m & 2047;
                const int bh = b * 16 + h;
                float v = acc[ii][jj][i] + bias;
                if (t == 0) {
                    Q[((size_t)bh * 2048 + s) * 64 + d] = __float2bfloat16(v * QSCALE);
                } else if (t == 1) {
                    K[((size_t)bh * 2048 + s) * 64 + d] = __float2bfloat16(v);
                } else {
                    Vt[((size_t)bh * 64 + d) * 2048 + s] = __float2bfloat16(v);
                }
            }
        }
    }
}

// ---------------------------------------------------------------------------
// Kernel 2: transposed flash attention with cooperative K/V LDS staging.
// (unchanged from round 9) 512 blocks x 4 waves; 128 q/block; 32 keys/iter.
// ---------------------------------------------------------------------------
__global__ __launch_bounds__(256)
void attn_kernel(const __hip_bfloat16* __restrict__ Q,
                 const __hip_bfloat16* __restrict__ K,
                 const __hip_bfloat16* __restrict__ Vt,
                 __hip_bfloat16* __restrict__ AO) {
    __shared__ unsigned short Ks0[32 * 40];   // K d=[0,32), sigma-permuted rows
    __shared__ unsigned short Ks1[32 * 40];   // K d=[32,64)
    __shared__ unsigned short Vs[64 * 40];    // V^T [d][key]

    const int tid  = threadIdx.x;
    const int lane = tid & 63;
    const int wv   = tid >> 6;
    const int quad = lane >> 4;
    const int l16  = lane & 15;

    const int blk = blockIdx.x;          // 0..511
    const int xcd = blk & 7;
    const int sub = blk >> 3;            // 0..63
    const int bh  = xcd * 4 + (sub & 3); // same bh stays on one XCD
    const int qb  = sub >> 2;            // 0..15
    const int q0  = qb * 128 + wv * 32;  // 32 queries per wave
    const int b   = bh >> 4;
    const int h   = bh & 15;

    const __hip_bfloat16* Qp = Q  + (size_t)bh * 131072;   // [S,D]
    const __hip_bfloat16* Kp = K  + (size_t)bh * 131072;   // [S,D]
    const __hip_bfloat16* Vp = Vt + (size_t)bh * 131072;   // [D,S]

    bf16x8 bQ[2][2];
#pragma unroll
    for (int t = 0; t < 2; ++t)
#pragma unroll
        for (int dh = 0; dh < 2; ++dh)
            bQ[t][dh] = ldg8(Qp + (size_t)(q0 + t * 16 + l16) * 64 + dh * 32 + quad * 8);

    const int kr = tid >> 3;
    const int kc = (tid & 7) * 8;
    const int kb = kr & 7;
    const int sig = (kb < 4) ? ((kr >> 3) * 4 + kb) : (16 + (kr >> 3) * 4 + (kb - 4));
    unsigned short* kw = (kc < 32) ? &Ks0[sig * 40 + kc] : &Ks1[sig * 40 + (kc - 32)];
    const int vr = tid >> 2;
    const int vc = (tid & 3) * 8;
    unsigned short* vw = &Vs[vr * 40 + vc];

    f32x4 zv = {0.f, 0.f, 0.f, 0.f};
    f32x4 Of[2][4];
#pragma unroll
    for (int t = 0; t < 2; ++t)
#pragma unroll
        for (int jj = 0; jj < 4; ++jj) Of[t][jj] = zv;
    float li[2] = {0.f, 0.f};

    for (int kt = 0; kt < 64; ++kt) {
        const int key0 = kt * 32;

        const bf16x8 gk = ldg8(Kp + (size_t)(key0 + kr) * 64 + kc);
        const bf16x8 gv = ldg8(Vp + (size_t)vr * 2048 + key0 + vc);
        __syncthreads();
        *reinterpret_cast<bf16x8*>(kw) = gk;
        *reinterpret_cast<bf16x8*>(vw) = gv;
        __syncthreads();

        const bf16x8 aKA0 = *reinterpret_cast<const bf16x8*>(&Ks0[l16 * 40 + quad * 8]);
        const bf16x8 aKA1 = *reinterpret_cast<const bf16x8*>(&Ks1[l16 * 40 + quad * 8]);
        const bf16x8 aKB0 = *reinterpret_cast<const bf16x8*>(&Ks0[(16 + l16) * 40 + quad * 8]);
        const bf16x8 aKB1 = *reinterpret_cast<const bf16x8*>(&Ks1[(16 + l16) * 40 + quad * 8]);
        bf16x8 aV[4];
#pragma unroll
        for (int jj = 0; jj < 4; ++jj)
            aV[jj] = *reinterpret_cast<const bf16x8*>(&Vs[(jj * 16 + l16) * 40 + quad * 8]);

        f32x4 sA[2], sB[2];
#pragma unroll
        for (int t = 0; t < 2; ++t) {
            sA[t] = zv; sB[t] = zv;
            sA[t] = MFMA16(aKA0, bQ[t][0], sA[t]);
            sA[t] = MFMA16(aKA1, bQ[t][1], sA[t]);
            sB[t] = MFMA16(aKB0, bQ[t][0], sB[t]);
            sB[t] = MFMA16(aKB1, bQ[t][1], sB[t]);
        }

#pragma unroll
        for (int t = 0; t < 2; ++t) {
            float pA[4], pB[4];
#pragma unroll
            for (int i = 0; i < 4; ++i) {
                pA[i] = EXP2F(sA[t][i]);
                pB[i] = EXP2F(sB[t][i]);
            }
            li[t] += ((pA[0] + pA[1]) + (pA[2] + pA[3]))
                   + ((pB[0] + pB[1]) + (pB[2] + pB[3]));

            bf16x8 bP;
            bP[0] = (short)f2bf_bits(pA[0]); bP[1] = (short)f2bf_bits(pA[1]);
            bP[2] = (short)f2bf_bits(pA[2]); bP[3] = (short)f2bf_bits(pA[3]);
            bP[4] = (short)f2bf_bits(pB[0]); bP[5] = (short)f2bf_bits(pB[1]);
            bP[6] = (short)f2bf_bits(pB[2]); bP[7] = (short)f2bf_bits(pB[3]);

#pragma unroll
            for (int jj = 0; jj < 4; ++jj)
                Of[t][jj] = MFMA16(aV[jj], bP, Of[t][jj]);
        }
    }

#pragma unroll
    for (int t = 0; t < 2; ++t) {
        li[t] += __shfl_xor(li[t], 16);
        li[t] += __shfl_xor(li[t], 32);
    }

#pragma unroll
    for (int t = 0; t < 2; ++t) {
        const float linv = 1.f / li[t];
        const int s = q0 + t * 16 + l16;
        __hip_bfloat16* aop = AO + (((size_t)b * 2048 + s) * 16 + h) * 64;
#pragma unroll
        for (int jj = 0; jj < 4; ++jj) {
            bf16x4 pk;
#pragma unroll
            for (int i = 0; i < 4; ++i)
                pk[i] = (short)f2bf_bits(Of[t][jj][i] * linv);
            *reinterpret_cast<bf16x4*>(aop + jj * 16 + quad * 4) = pk;
        }
    }
}

// ---------------------------------------------------------------------------
// Kernel 3: output projection, 128x128 tile, A=AO bf16, B=wob bf16.
// 1-D grid 256 = 8 xcd (n-tile) x 32 m-tiles.
// ---------------------------------------------------------------------------
__global__ __launch_bounds__(256)
void out_gemm(const __hip_bfloat16* __restrict__ A,
              const __hip_bfloat16* __restrict__ wob,
              const float* __restrict__ bo,
              float* __restrict__ out) {
    __shared__ unsigned short As[128 * 40];
    __shared__ unsigned short Bs[128 * 40];

    const int tid  = threadIdx.x;
    const int lane = tid & 63;
    const int wv   = tid >> 6;
    const int quad = lane >> 4;
    const int l16  = lane & 15;
    const int wm   = wv >> 1;
    const int wn   = wv & 1;

    const int bid = blockIdx.x;          // 0..255
    const int m0  = (bid >> 3) * 128;
    const int n0  = (bid & 7) * 128;

    const int sr = tid >> 1;
    const int sc = (tid & 1) * 16;
    const __hip_bfloat16* ag = A   + (size_t)(m0 + sr) * 1024 + sc;
    const __hip_bfloat16* bg = wob + (size_t)(n0 + sr) * 1024 + sc;
    unsigned short* aw = &As[sr * 40 + sc];
    unsigned short* bw = &Bs[sr * 40 + sc];

    f32x4 zv = {0.f, 0.f, 0.f, 0.f};
    f32x4 acc[4][4];
#pragma unroll
    for (int ii = 0; ii < 4; ++ii)
#pragma unroll
        for (int jj = 0; jj < 4; ++jj) acc[ii][jj] = zv;

    for (int k0 = 0; k0 < 1024; k0 += 32) {
        const bf16x8 av0 = ldg8(ag + k0), av1 = ldg8(ag + k0 + 8);
        const bf16x8 bv0 = ldg8(bg + k0), bv1 = ldg8(bg + k0 + 8);
        __syncthreads();
        reinterpret_cast<bf16x8*>(aw)[0] = av0;
        reinterpret_cast<bf16x8*>(aw)[1] = av1;
        reinterpret_cast<bf16x8*>(bw)[0] = bv0;
        reinterpret_cast<bf16x8*>(bw)[1] = bv1;
        __syncthreads();
        bf16x8 af[4], bf[4];
#pragma unroll
        for (int ii = 0; ii < 4; ++ii)
            af[ii] = *reinterpret_cast<const bf16x8*>(
                &As[(wm * 64 + ii * 16 + l16) * 40 + quad * 8]);
#pragma unroll
        for (int jj = 0; jj < 4; ++jj)
            bf[jj] = *reinterpret_cast<const bf16x8*>(
                &Bs[(wn * 64 + jj * 16 + l16) * 40 + quad * 8]);
#pragma unroll
        for (int ii = 0; ii < 4; ++ii)
#pragma unroll
            for (int jj = 0; jj < 4; ++jj)
                acc[ii][jj] = MFMA16(af[ii], bf[jj], acc[ii][jj]);
    }

#pragma unroll
    for (int jj = 0; jj < 4; ++jj) {
        const int n = n0 + wn * 64 + jj * 16 + l16;
        const float bias = bo[n];
#pragma unroll
        for (int ii = 0; ii < 4; ++ii) {
#pragma unroll
            for (int i = 0; i < 4; ++i) {
                const int m = m0 + wm * 64 + ii * 16 + quad * 4 + i;
                out[(size_t)m * 1024 + n] = acc[ii][jj][i] + bias;
            }
        }
    }
}

// ---------------------------------------------------------------------------
extern "C" void kernel_launch(void* const* d_in, const int* in_sizes, int n_in,
                              void* d_out, int out_size, void* d_ws, size_t ws_size,
                              hipStream_t stream) {
    const float* x    = (const float*)d_in[0];
    const float* wqkv = (const float*)d_in[1];
    const float* bqkv = (const float*)d_in[2];
    const float* wo   = (const float*)d_in[3];
    const float* bo   = (const float*)d_in[4];
    float* out = (float*)d_out;

    __hip_bfloat16* ws = (__hip_bfloat16*)d_ws;
    __hip_bfloat16* Q   = ws;                      // [32,2048,64] (x log2e/8)
    __hip_bfloat16* K   = ws + (size_t)4194304;
    __hip_bfloat16* Vt  = ws + (size_t)8388608;
    __hip_bfloat16* AO  = ws + (size_t)12582912;
    __hip_bfloat16* wob = Q;                       // overlay after attn

    // d_out doubles as pre-pass scratch (dead until out_gemm rewrites it):
    __hip_bfloat16* xb     = (__hip_bfloat16*)d_out;            // 4M elems, 8 MB
    __hip_bfloat16* wqkvb  = xb + (size_t)4194304;              // 3M elems, 6 MB

    // 0) casts: x (4M) and wqkv (3M) fp32 -> bf16 into d_out scratch
    cast_f32_bf16<<<dim3(512), 256, 0, stream>>>(x, xb);
    cast_f32_bf16<<<dim3(384), 256, 0, stream>>>(wqkv, wqkvb);
    // 1) QKV projection: M=4096, N=3072, K=1024; XCD-aware 1-D grid
    qkv_gemm<<<dim3(768), 256, 0, stream>>>(xb, wqkvb, bqkv, Q, K, Vt);
    // 2) attention: 32 bh x 16 q-blocks = 512 blocks
    attn_kernel<<<dim3(512), 256, 0, stream>>>(Q, K, Vt, AO);
    // 2b) wo fp32 -> bf16 into dead Q slot (1M elems)
    cast_f32_bf16<<<dim3(128), 256, 0, stream>>>(wo, wob);
    // 3) output projection: M=4096, N=1024, K=1024; XCD-aware grid
    out_gemm<<<dim3(256), 256, 0, stream>>>(AO, wob, bo, out);
}

// Round 11
// 203.222 us; speedup vs baseline: 1.0732x; 1.0732x over previous
//
#include <hip/hip_runtime.h>
#include <hip/hip_bf16.h>

// ---------------------------------------------------------------------------
// MultiheadAttention: x[2,2048,1024] fp32 -> out[2,2048,1024] fp32. H=16, D=64.
// Pipeline:
//   0) cast2   : x -> xb bf16, wqkv -> wqkvb bf16 into d_out scratch (dead
//                until out_gemm rewrites it; 8+6=14 MB <= 16 MB).
//   1) qkv_gemm: 128x128 bf16 MFMA GEMM with global_load_lds(16B) staging
//                (m97-style: direct HBM->LDS DMA, no VGPR round-trip).
//                LDS tiles UNPADDED (stride 32) — required by the wave-uniform
//                base + lane*16 landing rule (m104/m108); 8-way frag-read
//                conflicts accepted (same as m97 @ 874 TF).
//                -> Q (pre-scaled log2e/8), K [BH,S,D], Vt [BH,D,S] in ws.
//   2) attn    : transposed flash attention (unshifted base-2 softmax,
//                in-register P transpose), cooperative K/V LDS staging.
//                Unchanged from round 9.
//   2b) cast wo -> wob bf16 into Q slot (dead after attn).
//   3) out_gemm: 64x128 tile (512 blocks = 2/CU for latency hiding),
//                global_load_lds staging, fp32 out + bias.
// ws (32 MiB): [Q 8 | K 8 | Vt 8 | AO 8]; wob overlays Q after attn.
// MFMA 16x16x32 bf16 layouts (m89/m91 verified):
//   A-frag: lane holds A[m=lane&15][k=(lane>>4)*8+j]
//   B-frag: lane holds B[k=(lane>>4)*8+j][n=lane&15]
//   C/D   : lane holds D[row=(lane>>4)*4+i][col=lane&15]
// global_load_lds staging map (per wave, per 16-row call): lane l ->
//   global row base+ (l>>2), 16B chunk (l&3); lands at ldsbase + l*16B
//   == row-major rows [base, base+16) x 32 cols. LDS base wave-uniform.
// ---------------------------------------------------------------------------

typedef __attribute__((ext_vector_type(8))) short bf16x8;
typedef __attribute__((ext_vector_type(4))) short bf16x4;
typedef __attribute__((ext_vector_type(4))) float f32x4;

#define MFMA16(a, b, c) __builtin_amdgcn_mfma_f32_16x16x32_bf16((a), (b), (c), 0, 0, 0)

#if __has_builtin(__builtin_amdgcn_exp2f)
#define EXP2F(x) __builtin_amdgcn_exp2f(x)
#else
#define EXP2F(x) exp2f(x)
#endif

static __device__ __forceinline__ unsigned short f2bf_bits(float v) {
    __hip_bfloat16 h = __float2bfloat16(v);
    return *reinterpret_cast<unsigned short*>(&h);
}

static __device__ __forceinline__ bf16x8 cvt8(const float* p) {
    const f32x4 a = reinterpret_cast<const f32x4*>(p)[0];
    const f32x4 b = reinterpret_cast<const f32x4*>(p)[1];
    bf16x8 r;
    r[0] = (short)f2bf_bits(a[0]); r[1] = (short)f2bf_bits(a[1]);
    r[2] = (short)f2bf_bits(a[2]); r[3] = (short)f2bf_bits(a[3]);
    r[4] = (short)f2bf_bits(b[0]); r[5] = (short)f2bf_bits(b[1]);
    r[6] = (short)f2bf_bits(b[2]); r[7] = (short)f2bf_bits(b[3]);
    return r;
}

__device__ __forceinline__ bf16x8 ldg8(const __hip_bfloat16* p) {
    return *reinterpret_cast<const bf16x8*>(p);
}

// direct HBM -> LDS DMA, 16 B per lane; lds base must be wave-uniform
__device__ __forceinline__ void load16_lds(const __hip_bfloat16* g, unsigned short* l) {
    __builtin_amdgcn_global_load_lds(
        (const __attribute__((address_space(1))) void*)g,
        (__attribute__((address_space(3))) void*)l, 16, 0, 0);
}

// ---------------------------------------------------------------------------
// Kernel 0: merged cast. blocks [0,512) -> x (4M elems), [512,896) -> wqkv (3M).
// ---------------------------------------------------------------------------
__global__ __launch_bounds__(256)
void cast2_f32_bf16(const float* __restrict__ x, __hip_bfloat16* __restrict__ xb,
                    const float* __restrict__ w, __hip_bfloat16* __restrict__ wb) {
    const int bid = blockIdx.x;
    const float* src = (bid < 512) ? x : w;
    __hip_bfloat16* dst = (bid < 512) ? xb : wb;
    const int rb = (bid < 512) ? bid : (bid - 512);
    const size_t base = (size_t)rb * 8192 + (size_t)threadIdx.x * 32;
#pragma unroll
    for (int i = 0; i < 4; ++i)
        *reinterpret_cast<bf16x8*>(dst + base + i * 8) = cvt8(src + base + i * 8);
}

__global__ __launch_bounds__(256)
void cast_f32_bf16(const float* __restrict__ src, __hip_bfloat16* __restrict__ dst) {
    const size_t base = ((size_t)blockIdx.x * 256 + threadIdx.x) * 32;
#pragma unroll
    for (int i = 0; i < 4; ++i)
        *reinterpret_cast<bf16x8*>(dst + base + i * 8) = cvt8(src + base + i * 8);
}

// ---------------------------------------------------------------------------
// Kernel 1: QKV projection, 128x128 tile, global_load_lds staging.
// Q pre-scaled by (1/8)*log2(e).
// ---------------------------------------------------------------------------
__global__ __launch_bounds__(256)
void qkv_gemm(const __hip_bfloat16* __restrict__ xb,
              const __hip_bfloat16* __restrict__ wb,
              const float* __restrict__ bqkv,
              __hip_bfloat16* __restrict__ Q,
              __hip_bfloat16* __restrict__ K,
              __hip_bfloat16* __restrict__ Vt) {
    __shared__ unsigned short As[128 * 32];   // unpadded (global_load_lds rule)
    __shared__ unsigned short Bs[128 * 32];

    const int tid  = threadIdx.x;
    const int lane = tid & 63;
    const int wv   = tid >> 6;
    const int quad = lane >> 4;
    const int l16  = lane & 15;
    const int wm   = wv >> 1;
    const int wn   = wv & 1;

    const int bid = blockIdx.x;          // 0..767 (XCD-aware, neutral heuristic)
    const int xcd = bid & 7;
    const int r   = bid >> 3;            // 0..95
    const int m0  = (r / 3) * 128;
    const int n0  = (xcd * 3 + (r % 3)) * 128;

    // staging source pointers: lane l -> row base+(l>>2), 16B chunk (l&3)
    const __hip_bfloat16* agl = xb + (size_t)(m0 + wv * 32 + (lane >> 2)) * 1024 + (lane & 3) * 8;
    const __hip_bfloat16* bgl = wb + (size_t)(n0 + wv * 32 + (lane >> 2)) * 1024 + (lane & 3) * 8;
    unsigned short* al0 = &As[(wv * 32) * 32];
    unsigned short* al1 = &As[(wv * 32 + 16) * 32];
    unsigned short* bl0 = &Bs[(wv * 32) * 32];
    unsigned short* bl1 = &Bs[(wv * 32 + 16) * 32];

    f32x4 zv = {0.f, 0.f, 0.f, 0.f};
    f32x4 acc[4][4];
#pragma unroll
    for (int ii = 0; ii < 4; ++ii)
#pragma unroll
        for (int jj = 0; jj < 4; ++jj) acc[ii][jj] = zv;

    for (int k0 = 0; k0 < 1024; k0 += 32) {
        load16_lds(agl + k0, al0);
        load16_lds(agl + 16 * 1024 + k0, al1);
        load16_lds(bgl + k0, bl0);
        load16_lds(bgl + 16 * 1024 + k0, bl1);
        __syncthreads();                 // drain DMA; all lanes see tiles
        bf16x8 af[4], bf[4];
#pragma unroll
        for (int ii = 0; ii < 4; ++ii)
            af[ii] = *reinterpret_cast<const bf16x8*>(
                &As[(wm * 64 + ii * 16 + l16) * 32 + quad * 8]);
#pragma unroll
        for (int jj = 0; jj < 4; ++jj)
            bf[jj] = *reinterpret_cast<const bf16x8*>(
                &Bs[(wn * 64 + jj * 16 + l16) * 32 + quad * 8]);
#pragma unroll
        for (int ii = 0; ii < 4; ++ii)
#pragma unroll
            for (int jj = 0; jj < 4; ++jj)
                acc[ii][jj] = MFMA16(af[ii], bf[jj], acc[ii][jj]);
        __syncthreads();                 // reads done before next overwrite
    }

    const float QSCALE = 0.18033688011f;   // 0.125 * log2(e)

#pragma unroll
    for (int jj = 0; jj < 4; ++jj) {
        const int n = n0 + wn * 64 + jj * 16 + l16;
        const float bias = bqkv[n];
        const int h = n / 192;
        const int r2 = n - h * 192;
        const int t = r2 >> 6;              // 0=Q 1=K 2=V
        const int d = r2 & 63;
#pragma unroll
        for (int ii = 0; ii < 4; ++ii) {
#pragma unroll
            for (int i = 0; i < 4; ++i) {
                const int m = m0 + wm * 64 + ii * 16 + quad * 4 + i;
                const int b = m >> 11;
                const int s = m & 2047;
                const int bh = b * 16 + h;
                float v = acc[ii][jj][i] + bias;
                if (t == 0) {
                    Q[((size_t)bh * 2048 + s) * 64 + d] = __float2bfloat16(v * QSCALE);
                } else if (t == 1) {
                    K[((size_t)bh * 2048 + s) * 64 + d] = __float2bfloat16(v);
                } else {
                    Vt[((size_t)bh * 64 + d) * 2048 + s] = __float2bfloat16(v);
                }
            }
        }
    }
}

// ---------------------------------------------------------------------------
// Kernel 2: transposed flash attention with cooperative K/V LDS staging.
// (unchanged from round 9) 512 blocks x 4 waves; 128 q/block; 32 keys/iter.
// ---------------------------------------------------------------------------
__global__ __launch_bounds__(256)
void attn_kernel(const __hip_bfloat16* __restrict__ Q,
                 const __hip_bfloat16* __restrict__ K,
                 const __hip_bfloat16* __restrict__ Vt,
                 __hip_bfloat16* __restrict__ AO) {
    __shared__ unsigned short Ks0[32 * 40];   // K d=[0,32), sigma-permuted rows
    __shared__ unsigned short Ks1[32 * 40];   // K d=[32,64)
    __shared__ unsigned short Vs[64 * 40];    // V^T [d][key]

    const int tid  = threadIdx.x;
    const int lane = tid & 63;
    const int wv   = tid >> 6;
    const int quad = lane >> 4;
    const int l16  = lane & 15;

    const int blk = blockIdx.x;          // 0..511
    const int xcd = blk & 7;
    const int sub = blk >> 3;            // 0..63
    const int bh  = xcd * 4 + (sub & 3); // same bh stays on one XCD
    const int qb  = sub >> 2;            // 0..15
    const int q0  = qb * 128 + wv * 32;  // 32 queries per wave
    const int b   = bh >> 4;
    const int h   = bh & 15;

    const __hip_bfloat16* Qp = Q  + (size_t)bh * 131072;   // [S,D]
    const __hip_bfloat16* Kp = K  + (size_t)bh * 131072;   // [S,D]
    const __hip_bfloat16* Vp = Vt + (size_t)bh * 131072;   // [D,S]

    bf16x8 bQ[2][2];
#pragma unroll
    for (int t = 0; t < 2; ++t)
#pragma unroll
        for (int dh = 0; dh < 2; ++dh)
            bQ[t][dh] = ldg8(Qp + (size_t)(q0 + t * 16 + l16) * 64 + dh * 32 + quad * 8);

    const int kr = tid >> 3;
    const int kc = (tid & 7) * 8;
    const int kb = kr & 7;
    const int sig = (kb < 4) ? ((kr >> 3) * 4 + kb) : (16 + (kr >> 3) * 4 + (kb - 4));
    unsigned short* kw = (kc < 32) ? &Ks0[sig * 40 + kc] : &Ks1[sig * 40 + (kc - 32)];
    const int vr = tid >> 2;
    const int vc = (tid & 3) * 8;
    unsigned short* vw = &Vs[vr * 40 + vc];

    f32x4 zv = {0.f, 0.f, 0.f, 0.f};
    f32x4 Of[2][4];
#pragma unroll
    for (int t = 0; t < 2; ++t)
#pragma unroll
        for (int jj = 0; jj < 4; ++jj) Of[t][jj] = zv;
    float li[2] = {0.f, 0.f};

    for (int kt = 0; kt < 64; ++kt) {
        const int key0 = kt * 32;

        const bf16x8 gk = ldg8(Kp + (size_t)(key0 + kr) * 64 + kc);
        const bf16x8 gv = ldg8(Vp + (size_t)vr * 2048 + key0 + vc);
        __syncthreads();
        *reinterpret_cast<bf16x8*>(kw) = gk;
        *reinterpret_cast<bf16x8*>(vw) = gv;
        __syncthreads();

        const bf16x8 aKA0 = *reinterpret_cast<const bf16x8*>(&Ks0[l16 * 40 + quad * 8]);
        const bf16x8 aKA1 = *reinterpret_cast<const bf16x8*>(&Ks1[l16 * 40 + quad * 8]);
        const bf16x8 aKB0 = *reinterpret_cast<const bf16x8*>(&Ks0[(16 + l16) * 40 + quad * 8]);
        const bf16x8 aKB1 = *reinterpret_cast<const bf16x8*>(&Ks1[(16 + l16) * 40 + quad * 8]);
        bf16x8 aV[4];
#pragma unroll
        for (int jj = 0; jj < 4; ++jj)
            aV[jj] = *reinterpret_cast<const bf16x8*>(&Vs[(jj * 16 + l16) * 40 + quad * 8]);

        f32x4 sA[2], sB[2];
#pragma unroll
        for (int t = 0; t < 2; ++t) {
            sA[t] = zv; sB[t] = zv;
            sA[t] = MFMA16(aKA0, bQ[t][0], sA[t]);
            sA[t] = MFMA16(aKA1, bQ[t][1], sA[t]);
            sB[t] = MFMA16(aKB0, bQ[t][0], sB[t]);
            sB[t] = MFMA16(aKB1, bQ[t][1], sB[t]);
        }

#pragma unroll
        for (int t = 0; t < 2; ++t) {
            float pA[4], pB[4];
#pragma unroll
            for (int i = 0; i < 4; ++i) {
                pA[i] = EXP2F(sA[t][i]);
                pB[i] = EXP2F(sB[t][i]);
            }
            li[t] += ((pA[0] + pA[1]) + (pA[2] + pA[3]))
                   + ((pB[0] + pB[1]) + (pB[2] + pB[3]));

            bf16x8 bP;
            bP[0] = (short)f2bf_bits(pA[0]); bP[1] = (short)f2bf_bits(pA[1]);
            bP[2] = (short)f2bf_bits(pA[2]); bP[3] = (short)f2bf_bits(pA[3]);
            bP[4] = (short)f2bf_bits(pB[0]); bP[5] = (short)f2bf_bits(pB[1]);
            bP[6] = (short)f2bf_bits(pB[2]); bP[7] = (short)f2bf_bits(pB[3]);

#pragma unroll
            for (int jj = 0; jj < 4; ++jj)
                Of[t][jj] = MFMA16(aV[jj], bP, Of[t][jj]);
        }
    }

#pragma unroll
    for (int t = 0; t < 2; ++t) {
        li[t] += __shfl_xor(li[t], 16);
        li[t] += __shfl_xor(li[t], 32);
    }

#pragma unroll
    for (int t = 0; t < 2; ++t) {
        const float linv = 1.f / li[t];
        const int s = q0 + t * 16 + l16;
        __hip_bfloat16* aop = AO + (((size_t)b * 2048 + s) * 16 + h) * 64;
#pragma unroll
        for (int jj = 0; jj < 4; ++jj) {
            bf16x4 pk;
#pragma unroll
            for (int i = 0; i < 4; ++i)
                pk[i] = (short)f2bf_bits(Of[t][jj][i] * linv);
            *reinterpret_cast<bf16x4*>(aop + jj * 16 + quad * 4) = pk;
        }
    }
}

// ---------------------------------------------------------------------------
// Kernel 3: output projection, 64(M)x128(N) tile, global_load_lds staging.
// 512 blocks = 2 blocks/CU. Waves 2x2: wave tile 32(M)x64(N).
// ---------------------------------------------------------------------------
__global__ __launch_bounds__(256)
void out_gemm(const __hip_bfloat16* __restrict__ A,
              const __hip_bfloat16* __restrict__ wob,
              const float* __restrict__ bo,
              float* __restrict__ out) {
    __shared__ unsigned short As[64 * 32];    // unpadded
    __shared__ unsigned short Bs[128 * 32];

    const int tid  = threadIdx.x;
    const int lane = tid & 63;
    const int wv   = tid >> 6;
    const int quad = lane >> 4;
    const int l16  = lane & 15;
    const int wm   = wv >> 1;            // 0..1
    const int wn   = wv & 1;             // 0..1

    const int bid = blockIdx.x;          // 0..511
    const int m0  = (bid >> 3) * 64;
    const int n0  = (bid & 7) * 128;

    const __hip_bfloat16* agl = A   + (size_t)(m0 + wv * 16 + (lane >> 2)) * 1024 + (lane & 3) * 8;
    const __hip_bfloat16* bgl = wob + (size_t)(n0 + wv * 32 + (lane >> 2)) * 1024 + (lane & 3) * 8;
    unsigned short* al0 = &As[(wv * 16) * 32];
    unsigned short* bl0 = &Bs[(wv * 32) * 32];
    unsigned short* bl1 = &Bs[(wv * 32 + 16) * 32];

    f32x4 zv = {0.f, 0.f, 0.f, 0.f};
    f32x4 acc[2][4];
#pragma unroll
    for (int ii = 0; ii < 2; ++ii)
#pragma unroll
        for (int jj = 0; jj < 4; ++jj) acc[ii][jj] = zv;

    for (int k0 = 0; k0 < 1024; k0 += 32) {
        load16_lds(agl + k0, al0);
        load16_lds(bgl + k0, bl0);
        load16_lds(bgl + 16 * 1024 + k0, bl1);
        __syncthreads();
        bf16x8 af[2], bf[4];
#pragma unroll
        for (int ii = 0; ii < 2; ++ii)
            af[ii] = *reinterpret_cast<const bf16x8*>(
                &As[(wm * 32 + ii * 16 + l16) * 32 + quad * 8]);
#pragma unroll
        for (int jj = 0; jj < 4; ++jj)
            bf[jj] = *reinterpret_cast<const bf16x8*>(
                &Bs[(wn * 64 + jj * 16 + l16) * 32 + quad * 8]);
#pragma unroll
        for (int ii = 0; ii < 2; ++ii)
#pragma unroll
            for (int jj = 0; jj < 4; ++jj)
                acc[ii][jj] = MFMA16(af[ii], bf[jj], acc[ii][jj]);
        __syncthreads();
    }

#pragma unroll
    for (int jj = 0; jj < 4; ++jj) {
        const int n = n0 + wn * 64 + jj * 16 + l16;
        const float bias = bo[n];
#pragma unroll
        for (int ii = 0; ii < 2; ++ii) {
#pragma unroll
            for (int i = 0; i < 4; ++i) {
                const int m = m0 + wm * 32 + ii * 16 + quad * 4 + i;
                out[(size_t)m * 1024 + n] = acc[ii][jj][i] + bias;
            }
        }
    }
}

// ---------------------------------------------------------------------------
extern "C" void kernel_launch(void* const* d_in, const int* in_sizes, int n_in,
                              void* d_out, int out_size, void* d_ws, size_t ws_size,
                              hipStream_t stream) {
    const float* x    = (const float*)d_in[0];
    const float* wqkv = (const float*)d_in[1];
    const float* bqkv = (const float*)d_in[2];
    const float* wo   = (const float*)d_in[3];
    const float* bo   = (const float*)d_in[4];
    float* out = (float*)d_out;

    __hip_bfloat16* ws = (__hip_bfloat16*)d_ws;
    __hip_bfloat16* Q   = ws;                      // [32,2048,64] (x log2e/8)
    __hip_bfloat16* K   = ws + (size_t)4194304;
    __hip_bfloat16* Vt  = ws + (size_t)8388608;
    __hip_bfloat16* AO  = ws + (size_t)12582912;
    __hip_bfloat16* wob = Q;                       // overlay after attn

    // d_out doubles as pre-pass scratch (dead until out_gemm rewrites it):
    __hip_bfloat16* xb     = (__hip_bfloat16*)d_out;            // 4M elems, 8 MB
    __hip_bfloat16* wqkvb  = xb + (size_t)4194304;              // 3M elems, 6 MB

    // 0) merged casts: x (512 blocks) + wqkv (384 blocks)
    cast2_f32_bf16<<<dim3(896), 256, 0, stream>>>(x, xb, wqkv, wqkvb);
    // 1) QKV projection: M=4096, N=3072, K=1024
    qkv_gemm<<<dim3(768), 256, 0, stream>>>(xb, wqkvb, bqkv, Q, K, Vt);
    // 2) attention: 32 bh x 16 q-blocks = 512 blocks
    attn_kernel<<<dim3(512), 256, 0, stream>>>(Q, K, Vt, AO);
    // 2b) wo fp32 -> bf16 into dead Q slot (1M elems)
    cast_f32_bf16<<<dim3(128), 256, 0, stream>>>(wo, wob);
    // 3) output projection: M=4096, N=1024, K=1024
    out_gemm<<<dim3(512), 256, 0, stream>>>(AO, wob, bo, out);
}

// Round 12
// 200.550 us; speedup vs baseline: 1.0875x; 1.0133x over previous
//
#include <hip/hip_runtime.h>
#include <hip/hip_bf16.h>

// ---------------------------------------------------------------------------
// MultiheadAttention: x[2,2048,1024] fp32 -> out[2,2048,1024] fp32. H=16, D=64.
// Round 12: software-pipelined staging everywhere — issue next tile's loads
// BEFORE computing the current tile; double-buffered LDS; ONE barrier/iter.
//   0) cast2   : x -> xb bf16, wqkv -> wqkvb bf16 into d_out scratch.
//   1) qkv_gemm: 128x128 bf16 MFMA GEMM, global_load_lds(16B) DMA staging,
//                double-buffered (DMA k+1 before compute k). Unpadded LDS
//                (DMA landing rule m104/m108). -> Q (x log2e/8), K, Vt.
//   2) attn    : transposed flash attention (unshifted base-2 softmax,
//                in-register P transpose), K/V staged via VGPR prefetch +
//                double-buffered LDS, 1 barrier/iter.
//   2b) cast wo -> wob bf16 (Q slot, dead after attn).
//   3) out_gemm: 64x128 tile, DMA double-buffered like qkv.
// ws (32 MiB): [Q 8 | K 8 | Vt 8 | AO 8]; wob overlays Q after attn.
// MFMA 16x16x32 bf16 layouts (m89/m91 verified):
//   A-frag: lane holds A[m=lane&15][k=(lane>>4)*8+j]
//   B-frag: lane holds B[k=(lane>>4)*8+j][n=lane&15]
//   C/D   : lane holds D[row=(lane>>4)*4+i][col=lane&15]
// ---------------------------------------------------------------------------

typedef __attribute__((ext_vector_type(8))) short bf16x8;
typedef __attribute__((ext_vector_type(4))) short bf16x4;
typedef __attribute__((ext_vector_type(4))) float f32x4;

#define MFMA16(a, b, c) __builtin_amdgcn_mfma_f32_16x16x32_bf16((a), (b), (c), 0, 0, 0)

#if __has_builtin(__builtin_amdgcn_exp2f)
#define EXP2F(x) __builtin_amdgcn_exp2f(x)
#else
#define EXP2F(x) exp2f(x)
#endif

static __device__ __forceinline__ unsigned short f2bf_bits(float v) {
    __hip_bfloat16 h = __float2bfloat16(v);
    return *reinterpret_cast<unsigned short*>(&h);
}

static __device__ __forceinline__ bf16x8 cvt8(const float* p) {
    const f32x4 a = reinterpret_cast<const f32x4*>(p)[0];
    const f32x4 b = reinterpret_cast<const f32x4*>(p)[1];
    bf16x8 r;
    r[0] = (short)f2bf_bits(a[0]); r[1] = (short)f2bf_bits(a[1]);
    r[2] = (short)f2bf_bits(a[2]); r[3] = (short)f2bf_bits(a[3]);
    r[4] = (short)f2bf_bits(b[0]); r[5] = (short)f2bf_bits(b[1]);
    r[6] = (short)f2bf_bits(b[2]); r[7] = (short)f2bf_bits(b[3]);
    return r;
}

__device__ __forceinline__ bf16x8 ldg8(const __hip_bfloat16* p) {
    return *reinterpret_cast<const bf16x8*>(p);
}

// direct HBM -> LDS DMA, 16 B per lane; lds base must be wave-uniform
__device__ __forceinline__ void load16_lds(const __hip_bfloat16* g, unsigned short* l) {
    __builtin_amdgcn_global_load_lds(
        (const __attribute__((address_space(1))) void*)g,
        (__attribute__((address_space(3))) void*)l, 16, 0, 0);
}

// ---------------------------------------------------------------------------
// Kernel 0: merged cast. blocks [0,512) -> x (4M elems), [512,896) -> wqkv (3M).
// ---------------------------------------------------------------------------
__global__ __launch_bounds__(256)
void cast2_f32_bf16(const float* __restrict__ x, __hip_bfloat16* __restrict__ xb,
                    const float* __restrict__ w, __hip_bfloat16* __restrict__ wb) {
    const int bid = blockIdx.x;
    const float* src = (bid < 512) ? x : w;
    __hip_bfloat16* dst = (bid < 512) ? xb : wb;
    const int rb = (bid < 512) ? bid : (bid - 512);
    const size_t base = (size_t)rb * 8192 + (size_t)threadIdx.x * 32;
#pragma unroll
    for (int i = 0; i < 4; ++i)
        *reinterpret_cast<bf16x8*>(dst + base + i * 8) = cvt8(src + base + i * 8);
}

__global__ __launch_bounds__(256)
void cast_f32_bf16(const float* __restrict__ src, __hip_bfloat16* __restrict__ dst) {
    const size_t base = ((size_t)blockIdx.x * 256 + threadIdx.x) * 32;
#pragma unroll
    for (int i = 0; i < 4; ++i)
        *reinterpret_cast<bf16x8*>(dst + base + i * 8) = cvt8(src + base + i * 8);
}

// ---------------------------------------------------------------------------
// Kernel 1: QKV projection, 128x128 tile, double-buffered DMA staging.
// Q pre-scaled by (1/8)*log2(e).
// ---------------------------------------------------------------------------
__global__ __launch_bounds__(256)
void qkv_gemm(const __hip_bfloat16* __restrict__ xb,
              const __hip_bfloat16* __restrict__ wb,
              const float* __restrict__ bqkv,
              __hip_bfloat16* __restrict__ Q,
              __hip_bfloat16* __restrict__ K,
              __hip_bfloat16* __restrict__ Vt) {
    __shared__ unsigned short As[2][128 * 32];   // unpadded (DMA landing rule)
    __shared__ unsigned short Bs[2][128 * 32];

    const int tid  = threadIdx.x;
    const int lane = tid & 63;
    const int wv   = tid >> 6;
    const int quad = lane >> 4;
    const int l16  = lane & 15;
    const int wm   = wv >> 1;
    const int wn   = wv & 1;

    const int bid = blockIdx.x;          // 0..767
    const int xcd = bid & 7;
    const int r   = bid >> 3;            // 0..95
    const int m0  = (r / 3) * 128;
    const int n0  = (xcd * 3 + (r % 3)) * 128;

    // DMA source: lane l -> row base+(l>>2), 16B chunk (l&3)
    const __hip_bfloat16* agl = xb + (size_t)(m0 + wv * 32 + (lane >> 2)) * 1024 + (lane & 3) * 8;
    const __hip_bfloat16* bgl = wb + (size_t)(n0 + wv * 32 + (lane >> 2)) * 1024 + (lane & 3) * 8;

    f32x4 zv = {0.f, 0.f, 0.f, 0.f};
    f32x4 acc[4][4];
#pragma unroll
    for (int ii = 0; ii < 4; ++ii)
#pragma unroll
        for (int jj = 0; jj < 4; ++jj) acc[ii][jj] = zv;

    // prologue: DMA tile 0 into buffer 0
    load16_lds(agl, &As[0][(wv * 32) * 32]);
    load16_lds(agl + 16 * 1024, &As[0][(wv * 32 + 16) * 32]);
    load16_lds(bgl, &Bs[0][(wv * 32) * 32]);
    load16_lds(bgl + 16 * 1024, &Bs[0][(wv * 32 + 16) * 32]);
    __syncthreads();

    for (int k0 = 0; k0 < 1024; k0 += 32) {
        const int p = (k0 >> 5) & 1;
        // prefetch next tile into the other buffer BEFORE compute
        if (k0 + 32 < 1024) {
            const int q = p ^ 1;
            load16_lds(agl + k0 + 32, &As[q][(wv * 32) * 32]);
            load16_lds(agl + 16 * 1024 + k0 + 32, &As[q][(wv * 32 + 16) * 32]);
            load16_lds(bgl + k0 + 32, &Bs[q][(wv * 32) * 32]);
            load16_lds(bgl + 16 * 1024 + k0 + 32, &Bs[q][(wv * 32 + 16) * 32]);
        }
        bf16x8 af[4], bf[4];
#pragma unroll
        for (int ii = 0; ii < 4; ++ii)
            af[ii] = *reinterpret_cast<const bf16x8*>(
                &As[p][(wm * 64 + ii * 16 + l16) * 32 + quad * 8]);
#pragma unroll
        for (int jj = 0; jj < 4; ++jj)
            bf[jj] = *reinterpret_cast<const bf16x8*>(
                &Bs[p][(wn * 64 + jj * 16 + l16) * 32 + quad * 8]);
#pragma unroll
        for (int ii = 0; ii < 4; ++ii)
#pragma unroll
            for (int jj = 0; jj < 4; ++jj)
                acc[ii][jj] = MFMA16(af[ii], bf[jj], acc[ii][jj]);
        __syncthreads();   // drains DMA (mostly overlapped) + guards reuse
    }

    const float QSCALE = 0.18033688011f;   // 0.125 * log2(e)

#pragma unroll
    for (int jj = 0; jj < 4; ++jj) {
        const int n = n0 + wn * 64 + jj * 16 + l16;
        const float bias = bqkv[n];
        const int h = n / 192;
        const int r2 = n - h * 192;
        const int t = r2 >> 6;              // 0=Q 1=K 2=V
        const int d = r2 & 63;
#pragma unroll
        for (int ii = 0; ii < 4; ++ii) {
            const int mb = m0 + wm * 64 + ii * 16 + quad * 4;  // 4 consecutive m
            const int b = mb >> 11;
            const int s0 = mb & 2047;
            const int bh = b * 16 + h;
            if (t == 2) {
                bf16x4 pk;
#pragma unroll
                for (int i = 0; i < 4; ++i)
                    pk[i] = (short)f2bf_bits(acc[ii][jj][i] + bias);
                *reinterpret_cast<bf16x4*>(&Vt[((size_t)bh * 64 + d) * 2048 + s0]) = pk;
            } else {
#pragma unroll
                for (int i = 0; i < 4; ++i) {
                    const float v = acc[ii][jj][i] + bias;
                    if (t == 0)
                        Q[((size_t)bh * 2048 + s0 + i) * 64 + d] = __float2bfloat16(v * QSCALE);
                    else
                        K[((size_t)bh * 2048 + s0 + i) * 64 + d] = __float2bfloat16(v);
                }
            }
        }
    }
}

// ---------------------------------------------------------------------------
// Kernel 2: transposed flash attention, pipelined K/V staging.
// 512 blocks x 4 waves; 128 q/block; 32 keys/iter; double-buffered LDS,
// VGPR prefetch one tile ahead, ONE barrier per iteration.
// ---------------------------------------------------------------------------
__global__ __launch_bounds__(256)
void attn_kernel(const __hip_bfloat16* __restrict__ Q,
                 const __hip_bfloat16* __restrict__ K,
                 const __hip_bfloat16* __restrict__ Vt,
                 __hip_bfloat16* __restrict__ AO) {
    __shared__ unsigned short Ks0[2][32 * 40];   // K d=[0,32), sigma-permuted
    __shared__ unsigned short Ks1[2][32 * 40];   // K d=[32,64)
    __shared__ unsigned short Vs[2][64 * 40];    // V^T [d][key]

    const int tid  = threadIdx.x;
    const int lane = tid & 63;
    const int wv   = tid >> 6;
    const int quad = lane >> 4;
    const int l16  = lane & 15;

    const int blk = blockIdx.x;          // 0..511
    const int xcd = blk & 7;
    const int sub = blk >> 3;            // 0..63
    const int bh  = xcd * 4 + (sub & 3);
    const int qb  = sub >> 2;            // 0..15
    const int q0  = qb * 128 + wv * 32;
    const int b   = bh >> 4;
    const int h   = bh & 15;

    const __hip_bfloat16* Qp = Q  + (size_t)bh * 131072;   // [S,D]
    const __hip_bfloat16* Kp = K  + (size_t)bh * 131072;   // [S,D]
    const __hip_bfloat16* Vp = Vt + (size_t)bh * 131072;   // [D,S]

    bf16x8 bQ[2][2];
#pragma unroll
    for (int t = 0; t < 2; ++t)
#pragma unroll
        for (int dh = 0; dh < 2; ++dh)
            bQ[t][dh] = ldg8(Qp + (size_t)(q0 + t * 16 + l16) * 64 + dh * 32 + quad * 8);

    // staging thread map (as round 9)
    const int kr = tid >> 3;
    const int kc = (tid & 7) * 8;
    const int kb = kr & 7;
    const int sig = (kb < 4) ? ((kr >> 3) * 4 + kb) : (16 + (kr >> 3) * 4 + (kb - 4));
    const int koff = (kc < 32) ? (sig * 40 + kc) : (sig * 40 + (kc - 32));
    const int kis1 = (kc >= 32);
    const int vr = tid >> 2;
    const int vc = (tid & 3) * 8;
    const int voff = vr * 40 + vc;

    const __hip_bfloat16* kgp = Kp + (size_t)kr * 64 + kc;    // + key0*64
    const __hip_bfloat16* vgp = Vp + (size_t)vr * 2048 + vc;  // + key0

    f32x4 zv = {0.f, 0.f, 0.f, 0.f};
    f32x4 Of[2][4];
#pragma unroll
    for (int t = 0; t < 2; ++t)
#pragma unroll
        for (int jj = 0; jj < 4; ++jj) Of[t][jj] = zv;
    float li[2] = {0.f, 0.f};

    // prologue: tile 0 -> buf 0; prefetch tile 1 into regs
    bf16x8 gk = ldg8(kgp);                 // key0 = 0
    bf16x8 gv = ldg8(vgp);
    {
        unsigned short* kw0 = kis1 ? &Ks1[0][koff] : &Ks0[0][koff];
        *reinterpret_cast<bf16x8*>(kw0) = gk;
        *reinterpret_cast<bf16x8*>(&Vs[0][voff]) = gv;
    }
    gk = ldg8(kgp + (size_t)32 * 64);
    gv = ldg8(vgp + 32);
    __syncthreads();

    for (int kt = 0; kt < 64; ++kt) {
        const int p = kt & 1;
        // publish tile kt+1 (in regs) to the other buffer, then prefetch kt+2
        if (kt < 63) {
            unsigned short* kw1 = kis1 ? &Ks1[p ^ 1][koff] : &Ks0[p ^ 1][koff];
            *reinterpret_cast<bf16x8*>(kw1) = gk;
            *reinterpret_cast<bf16x8*>(&Vs[p ^ 1][voff]) = gv;
        }
        if (kt < 62) {
            gk = ldg8(kgp + (size_t)(kt + 2) * 32 * 64);
            gv = ldg8(vgp + (kt + 2) * 32);
        }

        const bf16x8 aKA0 = *reinterpret_cast<const bf16x8*>(&Ks0[p][l16 * 40 + quad * 8]);
        const bf16x8 aKA1 = *reinterpret_cast<const bf16x8*>(&Ks1[p][l16 * 40 + quad * 8]);
        const bf16x8 aKB0 = *reinterpret_cast<const bf16x8*>(&Ks0[p][(16 + l16) * 40 + quad * 8]);
        const bf16x8 aKB1 = *reinterpret_cast<const bf16x8*>(&Ks1[p][(16 + l16) * 40 + quad * 8]);
        bf16x8 aV[4];
#pragma unroll
        for (int jj = 0; jj < 4; ++jj)
            aV[jj] = *reinterpret_cast<const bf16x8*>(&Vs[p][(jj * 16 + l16) * 40 + quad * 8]);

        f32x4 sA[2], sB[2];
#pragma unroll
        for (int t = 0; t < 2; ++t) {
            sA[t] = zv; sB[t] = zv;
            sA[t] = MFMA16(aKA0, bQ[t][0], sA[t]);
            sA[t] = MFMA16(aKA1, bQ[t][1], sA[t]);
            sB[t] = MFMA16(aKB0, bQ[t][0], sB[t]);
            sB[t] = MFMA16(aKB1, bQ[t][1], sB[t]);
        }

#pragma unroll
        for (int t = 0; t < 2; ++t) {
            float pA[4], pB[4];
#pragma unroll
            for (int i = 0; i < 4; ++i) {
                pA[i] = EXP2F(sA[t][i]);
                pB[i] = EXP2F(sB[t][i]);
            }
            li[t] += ((pA[0] + pA[1]) + (pA[2] + pA[3]))
                   + ((pB[0] + pB[1]) + (pB[2] + pB[3]));

            bf16x8 bP;
            bP[0] = (short)f2bf_bits(pA[0]); bP[1] = (short)f2bf_bits(pA[1]);
            bP[2] = (short)f2bf_bits(pA[2]); bP[3] = (short)f2bf_bits(pA[3]);
            bP[4] = (short)f2bf_bits(pB[0]); bP[5] = (short)f2bf_bits(pB[1]);
            bP[6] = (short)f2bf_bits(pB[2]); bP[7] = (short)f2bf_bits(pB[3]);

#pragma unroll
            for (int jj = 0; jj < 4; ++jj)
                Of[t][jj] = MFMA16(aV[jj], bP, Of[t][jj]);
        }
        __syncthreads();   // single barrier: publishes buf[p^1], guards buf[p]
    }

#pragma unroll
    for (int t = 0; t < 2; ++t) {
        li[t] += __shfl_xor(li[t], 16);
        li[t] += __shfl_xor(li[t], 32);
    }

#pragma unroll
    for (int t = 0; t < 2; ++t) {
        const float linv = 1.f / li[t];
        const int s = q0 + t * 16 + l16;
        __hip_bfloat16* aop = AO + (((size_t)b * 2048 + s) * 16 + h) * 64;
#pragma unroll
        for (int jj = 0; jj < 4; ++jj) {
            bf16x4 pk;
#pragma unroll
            for (int i = 0; i < 4; ++i)
                pk[i] = (short)f2bf_bits(Of[t][jj][i] * linv);
            *reinterpret_cast<bf16x4*>(aop + jj * 16 + quad * 4) = pk;
        }
    }
}

// ---------------------------------------------------------------------------
// Kernel 3: output projection, 64(M)x128(N) tile, double-buffered DMA staging.
// 512 blocks = 2/CU. Waves 2x2: wave tile 32(M)x64(N).
// ---------------------------------------------------------------------------
__global__ __launch_bounds__(256)
void out_gemm(const __hip_bfloat16* __restrict__ A,
              const __hip_bfloat16* __restrict__ wob,
              const float* __restrict__ bo,
              float* __restrict__ out) {
    __shared__ unsigned short As[2][64 * 32];    // unpadded
    __shared__ unsigned short Bs[2][128 * 32];

    const int tid  = threadIdx.x;
    const int lane = tid & 63;
    const int wv   = tid >> 6;
    const int quad = lane >> 4;
    const int l16  = lane & 15;
    const int wm   = wv >> 1;
    const int wn   = wv & 1;

    const int bid = blockIdx.x;          // 0..511
    const int m0  = (bid >> 3) * 64;
    const int n0  = (bid & 7) * 128;

    const __hip_bfloat16* agl = A   + (size_t)(m0 + wv * 16 + (lane >> 2)) * 1024 + (lane & 3) * 8;
    const __hip_bfloat16* bgl = wob + (size_t)(n0 + wv * 32 + (lane >> 2)) * 1024 + (lane & 3) * 8;

    f32x4 zv = {0.f, 0.f, 0.f, 0.f};
    f32x4 acc[2][4];
#pragma unroll
    for (int ii = 0; ii < 2; ++ii)
#pragma unroll
        for (int jj = 0; jj < 4; ++jj) acc[ii][jj] = zv;

    load16_lds(agl, &As[0][(wv * 16) * 32]);
    load16_lds(bgl, &Bs[0][(wv * 32) * 32]);
    load16_lds(bgl + 16 * 1024, &Bs[0][(wv * 32 + 16) * 32]);
    __syncthreads();

    for (int k0 = 0; k0 < 1024; k0 += 32) {
        const int p = (k0 >> 5) & 1;
        if (k0 + 32 < 1024) {
            const int q = p ^ 1;
            load16_lds(agl + k0 + 32, &As[q][(wv * 16) * 32]);
            load16_lds(bgl + k0 + 32, &Bs[q][(wv * 32) * 32]);
            load16_lds(bgl + 16 * 1024 + k0 + 32, &Bs[q][(wv * 32 + 16) * 32]);
        }
        bf16x8 af[2], bf[4];
#pragma unroll
        for (int ii = 0; ii < 2; ++ii)
            af[ii] = *reinterpret_cast<const bf16x8*>(
                &As[p][(wm * 32 + ii * 16 + l16) * 32 + quad * 8]);
#pragma unroll
        for (int jj = 0; jj < 4; ++jj)
            bf[jj] = *reinterpret_cast<const bf16x8*>(
                &Bs[p][(wn * 64 + jj * 16 + l16) * 32 + quad * 8]);
#pragma unroll
        for (int ii = 0; ii < 2; ++ii)
#pragma unroll
            for (int jj = 0; jj < 4; ++jj)
                acc[ii][jj] = MFMA16(af[ii], bf[jj], acc[ii][jj]);
        __syncthreads();
    }

#pragma unroll
    for (int jj = 0; jj < 4; ++jj) {
        const int n = n0 + wn * 64 + jj * 16 + l16;
        const float bias = bo[n];
#pragma unroll
        for (int ii = 0; ii < 2; ++ii) {
#pragma unroll
            for (int i = 0; i < 4; ++i) {
                const int m = m0 + wm * 32 + ii * 16 + quad * 4 + i;
                out[(size_t)m * 1024 + n] = acc[ii][jj][i] + bias;
            }
        }
    }
}

// ---------------------------------------------------------------------------
extern "C" void kernel_launch(void* const* d_in, const int* in_sizes, int n_in,
                              void* d_out, int out_size, void* d_ws, size_t ws_size,
                              hipStream_t stream) {
    const float* x    = (const float*)d_in[0];
    const float* wqkv = (const float*)d_in[1];
    const float* bqkv = (const float*)d_in[2];
    const float* wo   = (const float*)d_in[3];
    const float* bo   = (const float*)d_in[4];
    float* out = (float*)d_out;

    __hip_bfloat16* ws = (__hip_bfloat16*)d_ws;
    __hip_bfloat16* Q   = ws;                      // [32,2048,64] (x log2e/8)
    __hip_bfloat16* K   = ws + (size_t)4194304;
    __hip_bfloat16* Vt  = ws + (size_t)8388608;
    __hip_bfloat16* AO  = ws + (size_t)12582912;
    __hip_bfloat16* wob = Q;                       // overlay after attn

    // d_out doubles as pre-pass scratch (dead until out_gemm rewrites it):
    __hip_bfloat16* xb     = (__hip_bfloat16*)d_out;            // 4M elems, 8 MB
    __hip_bfloat16* wqkvb  = xb + (size_t)4194304;              // 3M elems, 6 MB

    // 0) merged casts: x (512 blocks) + wqkv (384 blocks)
    cast2_f32_bf16<<<dim3(896), 256, 0, stream>>>(x, xb, wqkv, wqkvb);
    // 1) QKV projection: M=4096, N=3072, K=1024
    qkv_gemm<<<dim3(768), 256, 0, stream>>>(xb, wqkvb, bqkv, Q, K, Vt);
    // 2) attention: 32 bh x 16 q-blocks = 512 blocks
    attn_kernel<<<dim3(512), 256, 0, stream>>>(Q, K, Vt, AO);
    // 2b) wo fp32 -> bf16 into dead Q slot (1M elems)
    cast_f32_bf16<<<dim3(128), 256, 0, stream>>>(wo, wob);
    // 3) output projection: M=4096, N=1024, K=1024
    out_gemm<<<dim3(512), 256, 0, stream>>>(AO, wob, bo, out);
}